// Round 17
// baseline (313.312 us; speedup 1.0000x reference)
//
#include <hip/hip_runtime.h>
#include <math.h>

#define DI __device__ __forceinline__
#define HW128 (128*128)
#define HW256 (256*256)

__device__ const float BN_RS = 0.9999950000374997f; // 1/sqrt(1+1e-5)

DI float leakyf(float x){ return x >= 0.f ? x : 0.2f*x; }

DI unsigned short f2bf(float f){
    unsigned u = __float_as_uint(f);
    return (unsigned short)((u + 0x7fffu + ((u >> 16) & 1u)) >> 16);
}
DI float bf2f(unsigned short us){ return __uint_as_float((unsigned)us << 16); }
DI void unpack2(unsigned u, float& lo, float& hi){
    lo = __uint_as_float(u << 16);
    hi = __uint_as_float(u & 0xffff0000u);
}
DI void load8(const uint4* s, size_t idx, unsigned* d){
    uint4 t0 = s[idx], t1 = s[idx + 1];
    d[0]=t0.x; d[1]=t0.y; d[2]=t0.z; d[3]=t0.w;
    d[4]=t1.x; d[5]=t1.y; d[6]=t1.z; d[7]=t1.w;
}

typedef __attribute__((ext_vector_type(8))) short short8v;
typedef __attribute__((ext_vector_type(4))) float float4v;

// ---------------------------------------------------------------------------
// Prepack.
// ---------------------------------------------------------------------------
__global__ __launch_bounds__(256) void prepack(
    const float* __restrict__ w7a, const float* __restrict__ w1,
    const float* __restrict__ w3a, const float* __restrict__ b3a, const float* __restrict__ g3a, const float* __restrict__ be3a,
    const float* __restrict__ w3b, const float* __restrict__ b3b, const float* __restrict__ g3b, const float* __restrict__ be3b,
    const float* __restrict__ w3c, const float* __restrict__ b3c, const float* __restrict__ g3c, const float* __restrict__ be3c,
    const float* __restrict__ w7b, const float* __restrict__ fc1w, const float* __restrict__ fc2w,
    unsigned short* __restrict__ p7aB, float* __restrict__ p1,
    float* __restrict__ q3a, float* __restrict__ q3b, float* __restrict__ q3c,
    unsigned short* __restrict__ w3aB, unsigned short* __restrict__ w3bB, unsigned short* __restrict__ w3cB,
    unsigned short* __restrict__ pwB,
    unsigned short* __restrict__ pwT1, unsigned short* __restrict__ pwT2)
{
    int i = blockIdx.x * 256 + threadIdx.x;
    if (i < 57344) {                                      // conv7a MFMA weights
        int g = i / 14336, rem = i - g*14336;
        int ks = rem >> 9, oc = (rem >> 5) & 15, k = rem & 31;
        int ky = ks >> 2, kx = ((ks & 3) << 1) + (k >> 4), ic = g*16 + (k & 15);
        p7aB[i] = (kx < 7) ? f2bf(w7a[(oc*64 + ic)*49 + ky*7 + kx]) : (unsigned short)0;
    }
    if (i < 57344) {                                      // conv7b MFMA weights
        int ks = i >> 11, oc = (i >> 5) & 63, k = i & 31;
        int ky = ks >> 2, kx = ((ks & 3) << 1) + (k >> 4), ic = k & 15;
        pwB[i] = (kx < 7) ? f2bf(w7b[((oc*16 + ic)*7 + ky)*7 + kx]) : (unsigned short)0;
    }
    if (i < 3072) {                                       // conv3 MFMA weights ×3
        int ks = i >> 9, oc = (i >> 5) & 15, k = i & 31;
        int ky = ks >> 1, kx = ((ks & 1) << 1) + (k >> 4), ic = k & 15;
        if (kx < 3) {
            int src = (oc*16 + ic)*9 + ky*3 + kx;
            w3aB[i] = f2bf(w3a[src] * (g3a[oc]*BN_RS));
            w3bB[i] = f2bf(w3b[src] * (g3b[oc]*BN_RS));
            w3cB[i] = f2bf(w3c[src] * (g3c[oc]*BN_RS));
        } else {
            w3aB[i] = 0; w3bB[i] = 0; w3cB[i] = 0;
        }
    }
    if (i < 256) { int oc = i & 15, ic = i >> 4; p1[i] = w1[oc*16 + ic]; }
    if (i < 16) {
        q3a[i] = b3a[i]*(g3a[i]*BN_RS) + be3a[i];
        q3b[i] = b3b[i]*(g3b[i]*BN_RS) + be3b[i];
        q3c[i] = b3c[i]*(g3c[i]*BN_RS) + be3c[i];
    }
    if (i < 4096) { pwT1[i] = f2bf(fc1w[i]); pwT2[i] = f2bf(fc2w[i]); }
}

// ---------------------------------------------------------------------------
// x (8,64,128,128) f32 -> xci bf16 [n][g=ic/16][y*128+x][16]
// ---------------------------------------------------------------------------
__global__ __launch_bounds__(256) void x_to_ci(
    const float* __restrict__ x, unsigned short* __restrict__ xci)
{
    int idx = blockIdx.x*256 + threadIdx.x;   // 524,288
    int p = idx & 16383, gn = idx >> 14;
    int g = gn & 3, n = gn >> 2;
    const float* xb = x + (size_t)(n*64 + g*16)*HW128 + p;
    unsigned q[8];
#pragma unroll
    for (int h = 0; h < 8; ++h) {
        float a0 = xb[(size_t)(2*h)*HW128];
        float a1 = xb[(size_t)(2*h + 1)*HW128];
        q[h] = (unsigned)f2bf(a0) | ((unsigned)f2bf(a1) << 16);
    }
    uint4* dst = (uint4*)xci + (size_t)idx*2;
    dst[0] = make_uint4(q[0], q[1], q[2], q[3]);
    dst[1] = make_uint4(q[4], q[5], q[6], q[7]);
}

// ---------------------------------------------------------------------------
// conv7x7 64->16 MFMA + f32 1x1 + leaky + BN epilogue -> y2_ci bf16
// ---------------------------------------------------------------------------
__global__ __launch_bounds__(256) void conv7a_mfma(
    const unsigned short* __restrict__ xci,
    const unsigned short* __restrict__ pw,
    const float* __restrict__ b7a, const float* __restrict__ p1,
    const float* __restrict__ b1, const float* __restrict__ bng,
    const float* __restrict__ bnb, unsigned short* __restrict__ y2ci)
{
    __shared__ __align__(16) unsigned char lds[17408];
    unsigned short* tile = (unsigned short*)lds;   // [22][24][16] bf16
    float* P16 = (float*)lds;                      // [256][17] f32

    const int tid = threadIdx.x;
    const int n = blockIdx.z, ox = blockIdx.x*16, oy = blockIdx.y*16;
    const int w = tid >> 6, l = tid & 63, lg = l >> 4, ln = l & 15;

    float4v acc[4];
#pragma unroll
    for (int mi = 0; mi < 4; ++mi) acc[mi] = (float4v){0.f,0.f,0.f,0.f};

    const uint4* xc4 = (const uint4*)xci;
    uint4* tl4 = (uint4*)tile;
    const short8v* Bb = (const short8v*)pw;

    for (int g = 0; g < 4; ++g) {
        __syncthreads();
        for (int u = tid; u < 1056; u += 256) {
            int r = u / 48, s = u - r*48;
            int y = oy + r - 3, xcol = ox + (s >> 1) - 3;
            uint4 v = make_uint4(0u,0u,0u,0u);
            if (y >= 0 && y < 128 && xcol >= 0 && xcol < 128)
                v = xc4[((size_t)(n*4 + g)*16384 + y*128 + xcol)*2 + (s & 1)];
            tl4[u] = v;
        }
        __syncthreads();
        for (int ks = 0; ks < 28; ++ks) {
            const int ky = ks >> 2, kxp = (ks & 3) << 1;
            short8v b = Bb[(g*28 + ks)*64 + ln*4 + lg];
            short8v a[4];
#pragma unroll
            for (int mi = 0; mi < 4; ++mi) {
                int row = (4*w + mi) + ky;
                a[mi] = *(const short8v*)(tile + (row*24 + ln + kxp)*16 + lg*8);
            }
#pragma unroll
            for (int mi = 0; mi < 4; ++mi)
                acc[mi] = __builtin_amdgcn_mfma_f32_16x16x32_bf16(a[mi], b, acc[mi], 0, 0, 0);
        }
    }
    __syncthreads();
    const float bo = b7a[ln];
#pragma unroll
    for (int mi = 0; mi < 4; ++mi)
#pragma unroll
        for (int r = 0; r < 4; ++r)
            P16[((4*w + mi)*16 + lg*4 + r)*17 + ln] = leakyf(acc[mi][r] + bo);
    __syncthreads();
    const int py = tid >> 4, pxx = tid & 15;
    float lv[16];
#pragma unroll
    for (int ic = 0; ic < 16; ++ic) lv[ic] = P16[tid*17 + ic];
    float u16[16];
#pragma unroll
    for (int o = 0; o < 16; ++o) {
        float u = b1[o];
#pragma unroll
        for (int ic = 0; ic < 16; ++ic) u += lv[ic] * p1[ic*16 + o];
        u = leakyf(u);
        u16[o] = u * (bng[o]*BN_RS) + bnb[o];
    }
    const int p = (oy + py)*128 + ox + pxx;
    unsigned q[8];
#pragma unroll
    for (int h = 0; h < 8; ++h)
        q[h] = (unsigned)f2bf(u16[2*h]) | ((unsigned)f2bf(u16[2*h+1]) << 16);
    uint4* dst = (uint4*)y2ci + (size_t)(n*16384 + p)*2;
    dst[0] = make_uint4(q[0], q[1], q[2], q[3]);
    dst[1] = make_uint4(q[4], q[5], q[6], q[7]);
}

// ---------------------------------------------------------------------------
// Bilinear resize 128->256 on ci layout.
// ---------------------------------------------------------------------------
__global__ __launch_bounds__(256) void resize_ci(
    const unsigned short* __restrict__ y2ci, unsigned short* __restrict__ yci)
{
    const int n = blockIdx.z;
    const int ox = blockIdx.x*16 + threadIdx.x;
    const int oy = blockIdx.y*16 + threadIdx.y;
    float sy = oy * (127.f/255.f), sx = ox * (127.f/255.f);
    int y0 = min((int)sy, 126), x0 = min((int)sx, 126);
    float fy = sy - y0, fx = sx - x0;
    const uint4* src = (const uint4*)y2ci;
    size_t i00 = ((size_t)n*16384 + y0*128 + x0)*2;
    unsigned A00[8], A01[8], A10[8], A11[8];
    load8(src, i00,       A00);
    load8(src, i00 + 2,   A01);
    load8(src, i00 + 256, A10);
    load8(src, i00 + 258, A11);
    unsigned q[8];
#pragma unroll
    for (int h = 0; h < 8; ++h) {
        float l00, h00, l01, h01, l10, h10, l11, h11;
        unpack2(A00[h], l00, h00); unpack2(A01[h], l01, h01);
        unpack2(A10[h], l10, h10); unpack2(A11[h], l11, h11);
        float lo = (l00*(1.f-fx) + l01*fx)*(1.f-fy) + (l10*(1.f-fx) + l11*fx)*fy;
        float hi = (h00*(1.f-fx) + h01*fx)*(1.f-fy) + (h10*(1.f-fx) + h11*fx)*fy;
        q[h] = (unsigned)f2bf(lo) | ((unsigned)f2bf(hi) << 16);
    }
    uint4* dst = (uint4*)yci + ((size_t)n*65536 + oy*256 + ox)*2;
    dst[0] = make_uint4(q[0], q[1], q[2], q[3]);
    dst[1] = make_uint4(q[4], q[5], q[6], q[7]);
}

// ---------------------------------------------------------------------------
// 3x3 conv 16->16 via MFMA implicit GEMM on ci layout, BN pre-folded.
// ---------------------------------------------------------------------------
template<int MODE>
__global__ __launch_bounds__(256) void conv3_mfma(
    const unsigned short* __restrict__ in_ci,
    const unsigned short* __restrict__ wB, const float* __restrict__ q3,
    const unsigned short* __restrict__ res_ci,
    unsigned short* __restrict__ out_ci)
{
    __shared__ __align__(16) unsigned char lds[17408];
    unsigned short* tile = (unsigned short*)lds;   // [18][20][16] bf16
    float* P16 = (float*)lds;                      // [256][17] f32

    const int tid = threadIdx.x;
    const int n = blockIdx.z, ox = blockIdx.x*16, oy = blockIdx.y*16;
    const int w = tid >> 6, l = tid & 63, lg = l >> 4, ln = l & 15;

    const uint4* zc = (const uint4*)in_ci;
    uint4* tl4 = (uint4*)tile;
    for (int u = tid; u < 720; u += 256) {
        int r = u / 40, s = u - r*40;
        int y = oy + r - 1, xcol = ox + (s >> 1) - 1;
        uint4 v = make_uint4(0u,0u,0u,0u);
        if (y >= 0 && y < 256 && xcol >= 0 && xcol < 256)
            v = zc[((size_t)n*65536 + y*256 + xcol)*2 + (s & 1)];
        tl4[u] = v;
    }
    __syncthreads();

    float4v acc[4];
#pragma unroll
    for (int mi = 0; mi < 4; ++mi) acc[mi] = (float4v){0.f,0.f,0.f,0.f};
    const short8v* Bb = (const short8v*)wB;
#pragma unroll
    for (int ks = 0; ks < 6; ++ks) {
        const int ky = ks >> 1, kxp = (ks & 1) << 1;
        short8v b = Bb[(ks*16 + ln)*4 + lg];
        short8v a[4];
#pragma unroll
        for (int mi = 0; mi < 4; ++mi) {
            int row = (4*w + mi) + ky;
            a[mi] = *(const short8v*)(tile + (row*20 + ln + kxp)*16 + lg*8);
        }
#pragma unroll
        for (int mi = 0; mi < 4; ++mi)
            acc[mi] = __builtin_amdgcn_mfma_f32_16x16x32_bf16(a[mi], b, acc[mi], 0, 0, 0);
    }
    __syncthreads();
#pragma unroll
    for (int mi = 0; mi < 4; ++mi)
#pragma unroll
        for (int r = 0; r < 4; ++r)
            P16[((4*w + mi)*16 + lg*4 + r)*17 + ln] = acc[mi][r];
    __syncthreads();

    const int py = tid >> 4, pxx = tid & 15;
    const int p = (oy + py)*256 + ox + pxx;
    float u16[16];
#pragma unroll
    for (int o = 0; o < 16; ++o) u16[o] = P16[tid*17 + o] + q3[o];
    if (MODE == 0) {
#pragma unroll
        for (int o = 0; o < 16; ++o) u16[o] = leakyf(u16[o]);
    } else {
        unsigned R[8];
        load8((const uint4*)res_ci, ((size_t)n*65536 + p)*2, R);
#pragma unroll
        for (int h = 0; h < 8; ++h) {
            float lo, hi; unpack2(R[h], lo, hi);
            u16[2*h] += lo; u16[2*h+1] += hi;
        }
    }
    unsigned q[8];
#pragma unroll
    for (int h = 0; h < 8; ++h)
        q[h] = (unsigned)f2bf(u16[2*h]) | ((unsigned)f2bf(u16[2*h+1]) << 16);
    uint4* dst = (uint4*)out_ci + ((size_t)n*65536 + p)*2;
    dst[0] = make_uint4(q[0], q[1], q[2], q[3]);
    dst[1] = make_uint4(q[4], q[5], q[6], q[7]);
}

// ---------------------------------------------------------------------------
// conv7x7 16->64 MFMA + fused epilogue. R17: no xt16 LDS staging — bilinear
// neighbors read directly from global xci (bounds-free by clamp; L1/L2-hot).
// LDS 17,408 B -> 5+ blocks/CU. Writes bf16 oci; k logit from f32.
// ---------------------------------------------------------------------------
__global__ __launch_bounds__(256) void conv7b_mfma(
    const unsigned short* __restrict__ z_ci,
    const unsigned short* __restrict__ pwB,
    const unsigned short* __restrict__ xci,
    const float* __restrict__ bias,
    const float* __restrict__ akw, const float* __restrict__ akb,
    unsigned short* __restrict__ oci, float* __restrict__ kbuf)
{
    __shared__ __align__(16) unsigned char lds[17408];
    unsigned short* tile = (unsigned short*)lds;          // [22][24][16] bf16
    float* P16 = (float*)lds;                             // [256][17] f32 (aliases tile)

    const int tid = threadIdx.x;
    const int n = blockIdx.z, ox = blockIdx.x*16, oy = blockIdx.y*16;
    const float SC = 127.f/255.f;

    const uint4* zc = (const uint4*)z_ci;
    uint4* tl4 = (uint4*)tile;
    for (int u = tid; u < 1056; u += 256) {
        int r = u / 48, s = u - r*48;
        int y = oy + r - 3, xcol = ox + (s >> 1) - 3;
        uint4 v = make_uint4(0u, 0u, 0u, 0u);
        if (y >= 0 && y < 256 && xcol >= 0 && xcol < 256)
            v = zc[(size_t)((n*256 + y)*256 + xcol)*2 + (s & 1)];
        tl4[u] = v;
    }
    __syncthreads();

    const int w = tid >> 6, l = tid & 63;
    const int lg = l >> 4, ln = l & 15;
    float4v acc[4][4];
#pragma unroll
    for (int mi = 0; mi < 4; ++mi)
#pragma unroll
        for (int nt = 0; nt < 4; ++nt)
            acc[mi][nt] = (float4v){0.f, 0.f, 0.f, 0.f};

    const short8v* Bb = (const short8v*)pwB;
    for (int ks = 0; ks < 28; ++ks) {
        const int ky = ks >> 2, kxp = (ks & 3) << 1;
        short8v a[4], b[4];
#pragma unroll
        for (int mi = 0; mi < 4; ++mi) {
            int row = (4*w + mi) + ky;
            a[mi] = *(const short8v*)(tile + (row*24 + ln + kxp)*16 + lg*8);
        }
#pragma unroll
        for (int nt = 0; nt < 4; ++nt)
            b[nt] = Bb[ks*256 + nt*64 + ln*4 + lg];
#pragma unroll
        for (int mi = 0; mi < 4; ++mi)
#pragma unroll
            for (int nt = 0; nt < 4; ++nt)
                acc[mi][nt] = __builtin_amdgcn_mfma_f32_16x16x32_bf16(
                    a[mi], b[nt], acc[mi][nt], 0, 0, 0);
    }

    // epilogue: per-thread pixel; bilinear neighbors straight from xci
    const int py = tid >> 4, pxx = tid & 15;
    const int ohy = oy + py, ohx = ox + pxx;
    float sy = ohy*SC, sx = ohx*SC;
    int y0 = min((int)sy, 126), x0 = min((int)sx, 126);
    float fy = sy - y0, fx = sx - x0;
    const int p = ohy*256 + ohx;
    const uint4* xc4 = (const uint4*)xci;
    float kacc = akb[0];
    uint4* odst = (uint4*)oci + ((size_t)(n*65536 + p))*8;

    for (int nt = 0; nt < 4; ++nt) {
        __syncthreads();
#pragma unroll
        for (int mi = 0; mi < 4; ++mi)
#pragma unroll
            for (int r = 0; r < 4; ++r)
                P16[((4*w + mi)*16 + lg*4 + r)*17 + ln] = acc[mi][nt][r];
        __syncthreads();
        unsigned A00[8], A01[8], A10[8], A11[8];
        size_t b00 = ((size_t)(n*4 + nt)*16384 + y0*128 + x0)*2;
        load8(xc4, b00,       A00);
        load8(xc4, b00 + 2,   A01);
        load8(xc4, b00 + 256, A10);
        load8(xc4, b00 + 258, A11);
        float u16[16];
#pragma unroll
        for (int h = 0; h < 8; ++h) {
            float l00, h00, l01, h01, l10, h10, l11, h11;
            unpack2(A00[h], l00, h00); unpack2(A01[h], l01, h01);
            unpack2(A10[h], l10, h10); unpack2(A11[h], l11, h11);
            u16[2*h]   = (l00*(1.f-fx) + l01*fx)*(1.f-fy) + (l10*(1.f-fx) + l11*fx)*fy;
            u16[2*h+1] = (h00*(1.f-fx) + h01*fx)*(1.f-fy) + (h10*(1.f-fx) + h11*fx)*fy;
        }
        unsigned qpk[8];
#pragma unroll
        for (int o = 0; o < 16; ++o) {
            int oc = nt*16 + o;
            u16[o] = P16[tid*17 + o] + bias[oc] + u16[o];
            kacc += akw[oc] * u16[o];
        }
#pragma unroll
        for (int h = 0; h < 8; ++h)
            qpk[h] = (unsigned)f2bf(u16[2*h]) | ((unsigned)f2bf(u16[2*h+1]) << 16);
        odst[nt*2]     = make_uint4(qpk[0], qpk[1], qpk[2], qpk[3]);
        odst[nt*2 + 1] = make_uint4(qpk[4], qpk[5], qpk[6], qpk[7]);
    }
    kbuf[n*65536 + p] = kacc;
}

// ---------------------------------------------------------------------------
// Softmax stats, stage 1 + stage 2.
// ---------------------------------------------------------------------------
__global__ __launch_bounds__(256) void softmax_part(
    const float* __restrict__ kb, float* __restrict__ pst)
{
    __shared__ float red[4];
    __shared__ float bcast;
    const int pc = blockIdx.x, n = blockIdx.y, tid = threadIdx.x;
    const float* kp = kb + n*65536 + pc*8192;
    float mx = -3.0e38f;
    for (int i = tid; i < 8192; i += 256) mx = fmaxf(mx, kp[i]);
#pragma unroll
    for (int off = 1; off < 64; off <<= 1) mx = fmaxf(mx, __shfl_xor(mx, off));
    int w = tid >> 6, l = tid & 63;
    if (l == 0) red[w] = mx;
    __syncthreads();
    if (tid == 0) bcast = fmaxf(fmaxf(red[0], red[1]), fmaxf(red[2], red[3]));
    __syncthreads();
    float BM = bcast;
    float s = 0.f;
    for (int i = tid; i < 8192; i += 256) s += __expf(kp[i] - BM);
#pragma unroll
    for (int off = 1; off < 64; off <<= 1) s += __shfl_xor(s, off);
    __syncthreads();
    if (l == 0) red[w] = s;
    __syncthreads();
    if (tid == 0) {
        pst[(n*8 + pc)*2]     = BM;
        pst[(n*8 + pc)*2 + 1] = red[0] + red[1] + red[2] + red[3];
    }
}

__global__ __launch_bounds__(64) void softmax_comb(
    const float* __restrict__ pst, float* __restrict__ st)
{
    int tid = threadIdx.x;
    if (tid < 8) {
        int n = tid;
        float MX = -3.0e38f;
        for (int c = 0; c < 8; ++c) MX = fmaxf(MX, pst[(n*8 + c)*2]);
        float S = 0.f;
        for (int c = 0; c < 8; ++c)
            S += pst[(n*8 + c)*2 + 1] * __expf(pst[(n*8 + c)*2] - MX);
        st[n] = MX; st[8 + n] = 1.f / S;
    }
}

// ---------------------------------------------------------------------------
// att_wsum on ci layout: Sp[n][pc][c] = sum_{p in chunk} exp(k-mx)*oci[p][c].
// ---------------------------------------------------------------------------
__global__ __launch_bounds__(256) void att_wsum(
    const unsigned short* __restrict__ oci, const float* __restrict__ kb,
    const float* __restrict__ st, float* __restrict__ Sp)
{
    const int pc = blockIdx.x, n = blockIdx.y, tid = threadIdx.x;
    const int qr = tid & 3, pidx0 = tid >> 2;   // 0..63
    const float mx = st[n];
    float acc[16];
#pragma unroll
    for (int c = 0; c < 16; ++c) acc[c] = 0.f;
    const float* kp = kb + n*65536 + pc*2048;
    const uint4* base = (const uint4*)oci + ((size_t)(n*65536 + pc*2048))*8 + qr*2;
    for (int p = pidx0; p < 2048; p += 64) {
        float e = __expf(kp[p] - mx);
        uint4 t0 = base[(size_t)p*8], t1 = base[(size_t)p*8 + 1];
        unsigned d[8] = {t0.x, t0.y, t0.z, t0.w, t1.x, t1.y, t1.z, t1.w};
#pragma unroll
        for (int h = 0; h < 8; ++h) {
            float lo, hi; unpack2(d[h], lo, hi);
            acc[2*h] += e*lo; acc[2*h + 1] += e*hi;
        }
    }
#pragma unroll
    for (int c = 0; c < 16; ++c) {
        acc[c] += __shfl_xor(acc[c], 4);
        acc[c] += __shfl_xor(acc[c], 8);
        acc[c] += __shfl_xor(acc[c], 16);
        acc[c] += __shfl_xor(acc[c], 32);
    }
    __shared__ float red[4][4][16];   // [wave][qr][ch]
    int w = tid >> 6, l = tid & 63;
    if (l < 4) {
#pragma unroll
        for (int c = 0; c < 16; ++c) red[w][l][c] = acc[c];
    }
    __syncthreads();
    if (tid < 64) {
        int q2 = tid >> 4, c = tid & 15;
        Sp[n*2048 + pc*64 + q2*16 + c] =
            red[0][q2][c] + red[1][q2][c] + red[2][q2][c] + red[3][q2][c];
    }
}

// ---------------------------------------------------------------------------
// context + per-(n,c) attention addend (parallel 32-chunk reduce).
// ---------------------------------------------------------------------------
__global__ __launch_bounds__(512) void ctx_addc(
    const float* __restrict__ Sp, const float* __restrict__ st,
    const float* __restrict__ avw, const float* __restrict__ avb,
    const float* __restrict__ arw, const float* __restrict__ arb,
    float* __restrict__ addc)
{
    __shared__ float Sf[512];
    __shared__ float ctx[8][8];
    const int tid = threadIdx.x;
    {
        int n = tid >> 6, c = tid & 63;
        float s = 0.f;
        for (int k = 0; k < 32; ++k) s += Sp[n*2048 + k*64 + c];
        Sf[n*64 + c] = s;
    }
    __syncthreads();
    if (tid < 64) {
        int n = tid >> 3, vc = tid & 7;
        float s = 0.f;
        for (int c = 0; c < 64; ++c) s += avw[vc*64 + c] * Sf[n*64 + c];
        ctx[n][vc] = s * st[8 + n] + avb[vc];
    }
    __syncthreads();
    int n = tid >> 6, c = tid & 63;
    float a = arb[c];
#pragma unroll
    for (int vc = 0; vc < 8; ++vc) a += arw[c*8 + vc] * ctx[n][vc];
    addc[n*64 + c] = a;
}

// ---------------------------------------------------------------------------
// Transformer via MFMA (R16 verified: bf16 oci in, f32 d_out once).
// ---------------------------------------------------------------------------
__global__ __launch_bounds__(256) void transformer_mfma(
    const unsigned short* __restrict__ oci, float* __restrict__ out,
    const float* __restrict__ addc,
    const float* __restrict__ lng, const float* __restrict__ lnb,
    const unsigned short* __restrict__ W1b, const float* __restrict__ fc1b,
    const unsigned short* __restrict__ W2b, const float* __restrict__ fc2b)
{
    __shared__ __align__(16) unsigned char lds[8448 + 9216 + 2048 + 256];
    unsigned* Xci = (unsigned*)lds;                           // [64 tok][33] uint
    unsigned short* Xcis = (unsigned short*)lds;              // ushort view [tok*66 + c]
    unsigned short* Xb = (unsigned short*)(lds + 8448);       // [64 tok][72] bf16
    unsigned short* Hb = Xb;                                  // aliases Xb
    float* ps  = (float*)(lds + 8448 + 9216);                 // [4][64]
    float* ps2 = ps + 256;                                    // [4][64]
    float* ach = ps2 + 256;                                   // [64]

    const int tid = threadIdx.x;
    const int n = blockIdx.x >> 10;
    const int p0 = (blockIdx.x & 1023) << 6;

    if (tid < 64) ach[tid] = addc[n*64 + tid];

    // Phase 1: coalesced uint4 loads -> uint stores into Xci
    const uint4* src = (const uint4*)oci + (size_t)(n*65536 + p0)*8;
#pragma unroll
    for (int k = 0; k < 2; ++k) {
        int v = k*256 + tid;
        int tok = v >> 3, part = v & 7;
        uint4 t = src[(size_t)tok*8 + part];
        unsigned* du = Xci + tok*33 + part*4;
        du[0] = t.x; du[1] = t.y; du[2] = t.z; du[3] = t.w;
    }
    __syncthreads();

    // Phase 2a: thread owns (token = tid&63, quarter q = tid>>6)
    const int token = tid & 63, q = tid >> 6;
    float t16[16];
    {
        float sum = 0.f, sq = 0.f;
#pragma unroll
        for (int e = 0; e < 16; ++e) {
            float v = bf2f(Xcis[token*66 + q*16 + e]) + ach[q*16 + e];
            t16[e] = v; sum += v; sq += v*v;
        }
        ps[q*64 + token] = sum; ps2[q*64 + token] = sq;
    }
    __syncthreads();
    // Phase 2b: finalize LN for own quarter, write Xb from registers.
    {
        float sum = ps[token] + ps[64 + token] + ps[128 + token] + ps[192 + token];
        float sq  = ps2[token] + ps2[64 + token] + ps2[128 + token] + ps2[192 + token];
        float mu = sum * (1.f/64.f);
        float var = fmaxf(sq * (1.f/64.f) - mu*mu, 0.f);
        float rs = rsqrtf(var + 1e-5f);
#pragma unroll
        for (int c8 = 0; c8 < 2; ++c8) {
            short8v pk;
#pragma unroll
            for (int e = 0; e < 8; ++e) {
                int c = q*16 + c8*8 + e;
                pk[e] = (short)f2bf((t16[c8*8 + e] - mu)*rs*lng[c] + lnb[c]);
            }
            *(short8v*)&Xb[token*72 + q*16 + c8*8] = pk;
        }
    }
    __syncthreads();

    const int w = tid >> 6, l = tid & 63, lg = l >> 4, ln = l & 15;

    // Phase 3: GEMM1 (wave w owns tokens w*16..w*16+15)
    float4v acc1[4];
#pragma unroll
    for (int nt = 0; nt < 4; ++nt) acc1[nt] = (float4v){0.f,0.f,0.f,0.f};
#pragma unroll
    for (int kk = 0; kk < 2; ++kk) {
        short8v a = *(const short8v*)&Xb[(w*16 + ln)*72 + kk*32 + lg*8];
        short8v b[4];
#pragma unroll
        for (int nt = 0; nt < 4; ++nt)
            b[nt] = *(const short8v*)&W1b[(nt*16 + ln)*64 + kk*32 + lg*8];
#pragma unroll
        for (int nt = 0; nt < 4; ++nt)
            acc1[nt] = __builtin_amdgcn_mfma_f32_16x16x32_bf16(a, b[nt], acc1[nt], 0, 0, 0);
    }
    __syncthreads();   // all waves done reading Xb before Hb (=Xb) writes
#pragma unroll
    for (int nt = 0; nt < 4; ++nt) {
        int j = nt*16 + ln;
        float bj = fc1b[j];
#pragma unroll
        for (int r = 0; r < 4; ++r) {
            int tok = w*16 + lg*4 + r;
            float m = acc1[nt][r] + bj;
            float g = 0.5f*m*(1.f + erff(m*0.70710678118654752f));
            Hb[tok*72 + j] = f2bf(g);
        }
    }
    __syncthreads();

    // Phase 4: GEMM2 + epilogue (residual unpacked from Xci + addc)
    float4v acc2[4];
#pragma unroll
    for (int nt = 0; nt < 4; ++nt) acc2[nt] = (float4v){0.f,0.f,0.f,0.f};
#pragma unroll
    for (int kk = 0; kk < 2; ++kk) {
        short8v a = *(const short8v*)&Hb[(w*16 + ln)*72 + kk*32 + lg*8];
        short8v b[4];
#pragma unroll
        for (int nt = 0; nt < 4; ++nt)
            b[nt] = *(const short8v*)&W2b[(nt*16 + ln)*64 + kk*32 + lg*8];
#pragma unroll
        for (int nt = 0; nt < 4; ++nt)
            acc2[nt] = __builtin_amdgcn_mfma_f32_16x16x32_bf16(a, b[nt], acc2[nt], 0, 0, 0);
    }
#pragma unroll
    for (int nt = 0; nt < 4; ++nt) {
        int c = nt*16 + ln;
        int tb = w*16 + lg*4;
        float add = fc2b[c] + ach[c];
        float* dst = out + (size_t)(n*64 + c)*HW256 + p0 + tb;
        float4v o;
#pragma unroll
        for (int r = 0; r < 4; ++r)
            o[r] = bf2f(Xcis[(tb + r)*66 + c]) + add + acc2[nt][r];
        *(float4v*)dst = o;
    }
}

// ---------------------------------------------------------------------------
extern "C" void kernel_launch(void* const* d_in, const int* in_sizes, int n_in,
                              void* d_out, int out_size, void* d_ws, size_t ws_size,
                              hipStream_t stream)
{
    (void)in_sizes; (void)n_in; (void)out_size; (void)ws_size;
    const float* x    = (const float*)d_in[0];
    const float* w7a  = (const float*)d_in[1];
    const float* b7a  = (const float*)d_in[2];
    const float* w1   = (const float*)d_in[3];
    const float* b1   = (const float*)d_in[4];
    const float* g1   = (const float*)d_in[5];
    const float* be1  = (const float*)d_in[6];
    const float* w3a  = (const float*)d_in[7];
    const float* b3a  = (const float*)d_in[8];
    const float* g3a  = (const float*)d_in[9];
    const float* be3a = (const float*)d_in[10];
    const float* w3b  = (const float*)d_in[11];
    const float* b3b  = (const float*)d_in[12];
    const float* g3b  = (const float*)d_in[13];
    const float* be3b = (const float*)d_in[14];
    const float* w3c  = (const float*)d_in[15];
    const float* b3c  = (const float*)d_in[16];
    const float* g3c  = (const float*)d_in[17];
    const float* be3c = (const float*)d_in[18];
    const float* w7b  = (const float*)d_in[19];
    const float* b7b  = (const float*)d_in[20];
    const float* akw  = (const float*)d_in[21];
    const float* akb  = (const float*)d_in[22];
    const float* avw  = (const float*)d_in[25];
    const float* avb  = (const float*)d_in[26];
    const float* arw  = (const float*)d_in[27];
    const float* arb  = (const float*)d_in[28];
    const float* lng  = (const float*)d_in[29];
    const float* lnb  = (const float*)d_in[30];
    const float* fc1w = (const float*)d_in[31];
    const float* fc1b = (const float*)d_in[32];
    const float* fc2w = (const float*)d_in[33];
    const float* fc2b = (const float*)d_in[34];

    float* ws = (float*)d_ws;
    unsigned short* y2ci = (unsigned short*)ws;                         // 2,097,152 sh
    unsigned short* yci  = (unsigned short*)(ws + 1048576);             // 8,388,608 sh
    unsigned short* z1ci = (unsigned short*)(ws + 1048576 + 4194304);   // (z1/z3)
    unsigned short* z2ci = (unsigned short*)(ws + 1048576 + 2*4194304);
    unsigned short* xci  = (unsigned short*)(ws + 1048576 + 3*4194304); // persists
    unsigned short* oci  = (unsigned short*)(ws + 1048576 + 4*4194304); // [8][65536][64] bf16
    float* o_k   = ws + 1048576 + 4*4194304 + 16777216;  // 524,288
    float* o_st  = o_k + 524288;                // 64
    float* o_pst = o_st + 64;                   // 128
    float* o_Sp  = o_pst + 128;                 // 16,384
    float* o_ad  = o_Sp + 16384;                // 512
    unsigned short* p7aB = (unsigned short*)(o_ad + 512);   // 57,344 sh
    float* p1   = o_ad + 512 + 28672;           // 256
    float* q3a  = p1 + 256;
    float* q3b  = q3a + 16;
    float* q3c  = q3b + 16;
    unsigned short* w3aB = (unsigned short*)(q3c + 16);     // 3,072 sh each
    unsigned short* w3bB = w3aB + 3072;
    unsigned short* w3cB = w3bB + 3072;
    unsigned short* pwB  = w3cB + 3072;                     // 57,344 sh
    unsigned short* pwT1 = pwB + 57344;                     // 4,096 sh
    unsigned short* pwT2 = pwT1 + 4096;                     // 4,096 sh

    unsigned short* z3ci = z1ci;
    float* out0 = (float*)d_out;

    prepack<<<224, 256, 0, stream>>>(w7a, w1, w3a,b3a,g3a,be3a, w3b,b3b,g3b,be3b,
                                     w3c,b3c,g3c,be3c, w7b, fc1w, fc2w,
                                     p7aB, p1, q3a, q3b, q3c, w3aB, w3bB, w3cB,
                                     pwB, pwT1, pwT2);
    x_to_ci<<<2048, 256, 0, stream>>>(x, xci);
    conv7a_mfma<<<dim3(8,8,8), 256, 0, stream>>>(xci, p7aB, b7a, p1, b1, g1, be1, y2ci);
    resize_ci<<<dim3(16,16,8), dim3(16,16), 0, stream>>>(y2ci, yci);
    conv3_mfma<0><<<dim3(16,16,8), 256, 0, stream>>>(yci,  w3aB, q3a, nullptr, z1ci);
    conv3_mfma<1><<<dim3(16,16,8), 256, 0, stream>>>(z1ci, w3bB, q3b, yci,     z2ci);
    conv3_mfma<1><<<dim3(16,16,8), 256, 0, stream>>>(z2ci, w3cB, q3c, yci,     z3ci);
    conv7b_mfma<<<dim3(16,16,8), 256, 0, stream>>>(z3ci, pwB, xci, b7b, akw, akb, oci, o_k);
    softmax_part<<<dim3(8,8), 256, 0, stream>>>(o_k, o_pst);
    softmax_comb<<<1, 64, 0, stream>>>(o_pst, o_st);
    att_wsum<<<dim3(32,8), 256, 0, stream>>>(oci, o_k, o_st, o_Sp);
    ctx_addc<<<1, 512, 0, stream>>>(o_Sp, o_st, avw, avb, arw, arb, o_ad);
    transformer_mfma<<<8192, 256, 0, stream>>>(oci, out0, o_ad, lng, lnb, pwT1, fc1b, pwT2, fc2b);
}

// Round 18
// 311.299 us; speedup vs baseline: 1.0065x; 1.0065x over previous
//
#include <hip/hip_runtime.h>
#include <math.h>

#define DI __device__ __forceinline__
#define HW128 (128*128)
#define HW256 (256*256)

__device__ const float BN_RS = 0.9999950000374997f; // 1/sqrt(1+1e-5)

DI float leakyf(float x){ return x >= 0.f ? x : 0.2f*x; }

DI unsigned short f2bf(float f){
    unsigned u = __float_as_uint(f);
    return (unsigned short)((u + 0x7fffu + ((u >> 16) & 1u)) >> 16);
}
DI float bf2f(unsigned short us){ return __uint_as_float((unsigned)us << 16); }
DI void unpack2(unsigned u, float& lo, float& hi){
    lo = __uint_as_float(u << 16);
    hi = __uint_as_float(u & 0xffff0000u);
}
DI void load8(const uint4* s, size_t idx, unsigned* d){
    uint4 t0 = s[idx], t1 = s[idx + 1];
    d[0]=t0.x; d[1]=t0.y; d[2]=t0.z; d[3]=t0.w;
    d[4]=t1.x; d[5]=t1.y; d[6]=t1.z; d[7]=t1.w;
}

typedef __attribute__((ext_vector_type(8))) short short8v;
typedef __attribute__((ext_vector_type(4))) float float4v;

// ---------------------------------------------------------------------------
// Prepack.
// ---------------------------------------------------------------------------
__global__ __launch_bounds__(256) void prepack(
    const float* __restrict__ w7a, const float* __restrict__ w1,
    const float* __restrict__ w3a, const float* __restrict__ b3a, const float* __restrict__ g3a, const float* __restrict__ be3a,
    const float* __restrict__ w3b, const float* __restrict__ b3b, const float* __restrict__ g3b, const float* __restrict__ be3b,
    const float* __restrict__ w3c, const float* __restrict__ b3c, const float* __restrict__ g3c, const float* __restrict__ be3c,
    const float* __restrict__ w7b, const float* __restrict__ fc1w, const float* __restrict__ fc2w,
    unsigned short* __restrict__ p7aB, float* __restrict__ p1,
    float* __restrict__ q3a, float* __restrict__ q3b, float* __restrict__ q3c,
    unsigned short* __restrict__ w3aB, unsigned short* __restrict__ w3bB, unsigned short* __restrict__ w3cB,
    unsigned short* __restrict__ pwB,
    unsigned short* __restrict__ pwT1, unsigned short* __restrict__ pwT2)
{
    int i = blockIdx.x * 256 + threadIdx.x;
    if (i < 57344) {                                      // conv7a MFMA weights
        int g = i / 14336, rem = i - g*14336;
        int ks = rem >> 9, oc = (rem >> 5) & 15, k = rem & 31;
        int ky = ks >> 2, kx = ((ks & 3) << 1) + (k >> 4), ic = g*16 + (k & 15);
        p7aB[i] = (kx < 7) ? f2bf(w7a[(oc*64 + ic)*49 + ky*7 + kx]) : (unsigned short)0;
    }
    if (i < 57344) {                                      // conv7b MFMA weights
        int ks = i >> 11, oc = (i >> 5) & 63, k = i & 31;
        int ky = ks >> 2, kx = ((ks & 3) << 1) + (k >> 4), ic = k & 15;
        pwB[i] = (kx < 7) ? f2bf(w7b[((oc*16 + ic)*7 + ky)*7 + kx]) : (unsigned short)0;
    }
    if (i < 3072) {                                       // conv3 MFMA weights ×3
        int ks = i >> 9, oc = (i >> 5) & 15, k = i & 31;
        int ky = ks >> 1, kx = ((ks & 1) << 1) + (k >> 4), ic = k & 15;
        if (kx < 3) {
            int src = (oc*16 + ic)*9 + ky*3 + kx;
            w3aB[i] = f2bf(w3a[src] * (g3a[oc]*BN_RS));
            w3bB[i] = f2bf(w3b[src] * (g3b[oc]*BN_RS));
            w3cB[i] = f2bf(w3c[src] * (g3c[oc]*BN_RS));
        } else {
            w3aB[i] = 0; w3bB[i] = 0; w3cB[i] = 0;
        }
    }
    if (i < 256) { int oc = i & 15, ic = i >> 4; p1[i] = w1[oc*16 + ic]; }
    if (i < 16) {
        q3a[i] = b3a[i]*(g3a[i]*BN_RS) + be3a[i];
        q3b[i] = b3b[i]*(g3b[i]*BN_RS) + be3b[i];
        q3c[i] = b3c[i]*(g3c[i]*BN_RS) + be3c[i];
    }
    if (i < 4096) { pwT1[i] = f2bf(fc1w[i]); pwT2[i] = f2bf(fc2w[i]); }
}

// ---------------------------------------------------------------------------
// x (8,64,128,128) f32 -> xci bf16 [n][g=ic/16][y*128+x][16]
// ---------------------------------------------------------------------------
__global__ __launch_bounds__(256) void x_to_ci(
    const float* __restrict__ x, unsigned short* __restrict__ xci)
{
    int idx = blockIdx.x*256 + threadIdx.x;   // 524,288
    int p = idx & 16383, gn = idx >> 14;
    int g = gn & 3, n = gn >> 2;
    const float* xb = x + (size_t)(n*64 + g*16)*HW128 + p;
    unsigned q[8];
#pragma unroll
    for (int h = 0; h < 8; ++h) {
        float a0 = xb[(size_t)(2*h)*HW128];
        float a1 = xb[(size_t)(2*h + 1)*HW128];
        q[h] = (unsigned)f2bf(a0) | ((unsigned)f2bf(a1) << 16);
    }
    uint4* dst = (uint4*)xci + (size_t)idx*2;
    dst[0] = make_uint4(q[0], q[1], q[2], q[3]);
    dst[1] = make_uint4(q[4], q[5], q[6], q[7]);
}

// ---------------------------------------------------------------------------
// conv7x7 64->16 MFMA + f32 1x1 + leaky + BN epilogue -> y2_ci bf16
// ---------------------------------------------------------------------------
__global__ __launch_bounds__(256) void conv7a_mfma(
    const unsigned short* __restrict__ xci,
    const unsigned short* __restrict__ pw,
    const float* __restrict__ b7a, const float* __restrict__ p1,
    const float* __restrict__ b1, const float* __restrict__ bng,
    const float* __restrict__ bnb, unsigned short* __restrict__ y2ci)
{
    __shared__ __align__(16) unsigned char lds[17408];
    unsigned short* tile = (unsigned short*)lds;   // [22][24][16] bf16
    float* P16 = (float*)lds;                      // [256][17] f32

    const int tid = threadIdx.x;
    const int n = blockIdx.z, ox = blockIdx.x*16, oy = blockIdx.y*16;
    const int w = tid >> 6, l = tid & 63, lg = l >> 4, ln = l & 15;

    float4v acc[4];
#pragma unroll
    for (int mi = 0; mi < 4; ++mi) acc[mi] = (float4v){0.f,0.f,0.f,0.f};

    const uint4* xc4 = (const uint4*)xci;
    uint4* tl4 = (uint4*)tile;
    const short8v* Bb = (const short8v*)pw;

    for (int g = 0; g < 4; ++g) {
        __syncthreads();
        for (int u = tid; u < 1056; u += 256) {
            int r = u / 48, s = u - r*48;
            int y = oy + r - 3, xcol = ox + (s >> 1) - 3;
            uint4 v = make_uint4(0u,0u,0u,0u);
            if (y >= 0 && y < 128 && xcol >= 0 && xcol < 128)
                v = xc4[((size_t)(n*4 + g)*16384 + y*128 + xcol)*2 + (s & 1)];
            tl4[u] = v;
        }
        __syncthreads();
        for (int ks = 0; ks < 28; ++ks) {
            const int ky = ks >> 2, kxp = (ks & 3) << 1;
            short8v b = Bb[(g*28 + ks)*64 + ln*4 + lg];
            short8v a[4];
#pragma unroll
            for (int mi = 0; mi < 4; ++mi) {
                int row = (4*w + mi) + ky;
                a[mi] = *(const short8v*)(tile + (row*24 + ln + kxp)*16 + lg*8);
            }
#pragma unroll
            for (int mi = 0; mi < 4; ++mi)
                acc[mi] = __builtin_amdgcn_mfma_f32_16x16x32_bf16(a[mi], b, acc[mi], 0, 0, 0);
        }
    }
    __syncthreads();
    const float bo = b7a[ln];
#pragma unroll
    for (int mi = 0; mi < 4; ++mi)
#pragma unroll
        for (int r = 0; r < 4; ++r)
            P16[((4*w + mi)*16 + lg*4 + r)*17 + ln] = leakyf(acc[mi][r] + bo);
    __syncthreads();
    const int py = tid >> 4, pxx = tid & 15;
    float lv[16];
#pragma unroll
    for (int ic = 0; ic < 16; ++ic) lv[ic] = P16[tid*17 + ic];
    float u16[16];
#pragma unroll
    for (int o = 0; o < 16; ++o) {
        float u = b1[o];
#pragma unroll
        for (int ic = 0; ic < 16; ++ic) u += lv[ic] * p1[ic*16 + o];
        u = leakyf(u);
        u16[o] = u * (bng[o]*BN_RS) + bnb[o];
    }
    const int p = (oy + py)*128 + ox + pxx;
    unsigned q[8];
#pragma unroll
    for (int h = 0; h < 8; ++h)
        q[h] = (unsigned)f2bf(u16[2*h]) | ((unsigned)f2bf(u16[2*h+1]) << 16);
    uint4* dst = (uint4*)y2ci + (size_t)(n*16384 + p)*2;
    dst[0] = make_uint4(q[0], q[1], q[2], q[3]);
    dst[1] = make_uint4(q[4], q[5], q[6], q[7]);
}

// ---------------------------------------------------------------------------
// Bilinear resize 128->256 on ci layout.
// ---------------------------------------------------------------------------
__global__ __launch_bounds__(256) void resize_ci(
    const unsigned short* __restrict__ y2ci, unsigned short* __restrict__ yci)
{
    const int n = blockIdx.z;
    const int ox = blockIdx.x*16 + threadIdx.x;
    const int oy = blockIdx.y*16 + threadIdx.y;
    float sy = oy * (127.f/255.f), sx = ox * (127.f/255.f);
    int y0 = min((int)sy, 126), x0 = min((int)sx, 126);
    float fy = sy - y0, fx = sx - x0;
    const uint4* src = (const uint4*)y2ci;
    size_t i00 = ((size_t)n*16384 + y0*128 + x0)*2;
    unsigned A00[8], A01[8], A10[8], A11[8];
    load8(src, i00,       A00);
    load8(src, i00 + 2,   A01);
    load8(src, i00 + 256, A10);
    load8(src, i00 + 258, A11);
    unsigned q[8];
#pragma unroll
    for (int h = 0; h < 8; ++h) {
        float l00, h00, l01, h01, l10, h10, l11, h11;
        unpack2(A00[h], l00, h00); unpack2(A01[h], l01, h01);
        unpack2(A10[h], l10, h10); unpack2(A11[h], l11, h11);
        float lo = (l00*(1.f-fx) + l01*fx)*(1.f-fy) + (l10*(1.f-fx) + l11*fx)*fy;
        float hi = (h00*(1.f-fx) + h01*fx)*(1.f-fy) + (h10*(1.f-fx) + h11*fx)*fy;
        q[h] = (unsigned)f2bf(lo) | ((unsigned)f2bf(hi) << 16);
    }
    uint4* dst = (uint4*)yci + ((size_t)n*65536 + oy*256 + ox)*2;
    dst[0] = make_uint4(q[0], q[1], q[2], q[3]);
    dst[1] = make_uint4(q[4], q[5], q[6], q[7]);
}

// ---------------------------------------------------------------------------
// 3x3 conv 16->16 via MFMA implicit GEMM on ci layout, BN pre-folded.
// ---------------------------------------------------------------------------
template<int MODE>
__global__ __launch_bounds__(256) void conv3_mfma(
    const unsigned short* __restrict__ in_ci,
    const unsigned short* __restrict__ wB, const float* __restrict__ q3,
    const unsigned short* __restrict__ res_ci,
    unsigned short* __restrict__ out_ci)
{
    __shared__ __align__(16) unsigned char lds[17408];
    unsigned short* tile = (unsigned short*)lds;   // [18][20][16] bf16
    float* P16 = (float*)lds;                      // [256][17] f32

    const int tid = threadIdx.x;
    const int n = blockIdx.z, ox = blockIdx.x*16, oy = blockIdx.y*16;
    const int w = tid >> 6, l = tid & 63, lg = l >> 4, ln = l & 15;

    const uint4* zc = (const uint4*)in_ci;
    uint4* tl4 = (uint4*)tile;
    for (int u = tid; u < 720; u += 256) {
        int r = u / 40, s = u - r*40;
        int y = oy + r - 1, xcol = ox + (s >> 1) - 1;
        uint4 v = make_uint4(0u,0u,0u,0u);
        if (y >= 0 && y < 256 && xcol >= 0 && xcol < 256)
            v = zc[((size_t)n*65536 + y*256 + xcol)*2 + (s & 1)];
        tl4[u] = v;
    }
    __syncthreads();

    float4v acc[4];
#pragma unroll
    for (int mi = 0; mi < 4; ++mi) acc[mi] = (float4v){0.f,0.f,0.f,0.f};
    const short8v* Bb = (const short8v*)wB;
#pragma unroll
    for (int ks = 0; ks < 6; ++ks) {
        const int ky = ks >> 1, kxp = (ks & 1) << 1;
        short8v b = Bb[(ks*16 + ln)*4 + lg];
        short8v a[4];
#pragma unroll
        for (int mi = 0; mi < 4; ++mi) {
            int row = (4*w + mi) + ky;
            a[mi] = *(const short8v*)(tile + (row*20 + ln + kxp)*16 + lg*8);
        }
#pragma unroll
        for (int mi = 0; mi < 4; ++mi)
            acc[mi] = __builtin_amdgcn_mfma_f32_16x16x32_bf16(a[mi], b, acc[mi], 0, 0, 0);
    }
    __syncthreads();
#pragma unroll
    for (int mi = 0; mi < 4; ++mi)
#pragma unroll
        for (int r = 0; r < 4; ++r)
            P16[((4*w + mi)*16 + lg*4 + r)*17 + ln] = acc[mi][r];
    __syncthreads();

    const int py = tid >> 4, pxx = tid & 15;
    const int p = (oy + py)*256 + ox + pxx;
    float u16[16];
#pragma unroll
    for (int o = 0; o < 16; ++o) u16[o] = P16[tid*17 + o] + q3[o];
    if (MODE == 0) {
#pragma unroll
        for (int o = 0; o < 16; ++o) u16[o] = leakyf(u16[o]);
    } else {
        unsigned R[8];
        load8((const uint4*)res_ci, ((size_t)n*65536 + p)*2, R);
#pragma unroll
        for (int h = 0; h < 8; ++h) {
            float lo, hi; unpack2(R[h], lo, hi);
            u16[2*h] += lo; u16[2*h+1] += hi;
        }
    }
    unsigned q[8];
#pragma unroll
    for (int h = 0; h < 8; ++h)
        q[h] = (unsigned)f2bf(u16[2*h]) | ((unsigned)f2bf(u16[2*h+1]) << 16);
    uint4* dst = (uint4*)out_ci + ((size_t)n*65536 + p)*2;
    dst[0] = make_uint4(q[0], q[1], q[2], q[3]);
    dst[1] = make_uint4(q[4], q[5], q[6], q[7]);
}

// ---------------------------------------------------------------------------
// conv7x7 16->64 MFMA + fused epilogue (R16 verified best: xt16 LDS staging,
// bf16 oci output, VGPR 92, ~121 us).
// ---------------------------------------------------------------------------
__global__ __launch_bounds__(256) void conv7b_mfma(
    const unsigned short* __restrict__ z_ci,
    const unsigned short* __restrict__ pwB,
    const unsigned short* __restrict__ xci,
    const float* __restrict__ bias,
    const float* __restrict__ akw, const float* __restrict__ akb,
    unsigned short* __restrict__ oci, float* __restrict__ kbuf)
{
    __shared__ __align__(16) unsigned char lds[17408 + 14400];
    unsigned short* tile = (unsigned short*)lds;          // [22][24][16] bf16
    float* P16 = (float*)lds;                             // [256][17] f32 (aliases tile)
    unsigned short* xt16 = (unsigned short*)(lds + 17408);// [100 px][72] bf16 (pad 8)

    const int tid = threadIdx.x;
    const int n = blockIdx.z, ox = blockIdx.x*16, oy = blockIdx.y*16;
    const float SC = 127.f/255.f;
    const int ybase = (int)(oy*SC), xbase = (int)(ox*SC);

    const uint4* zc = (const uint4*)z_ci;
    uint4* tl4 = (uint4*)tile;
    for (int u = tid; u < 1056; u += 256) {
        int r = u / 48, s = u - r*48;
        int y = oy + r - 3, xcol = ox + (s >> 1) - 3;
        uint4 v = make_uint4(0u, 0u, 0u, 0u);
        if (y >= 0 && y < 256 && xcol >= 0 && xcol < 256)
            v = zc[(size_t)((n*256 + y)*256 + xcol)*2 + (s & 1)];
        tl4[u] = v;
    }
    const uint4* xc4 = (const uint4*)xci;
    uint4* xt4 = (uint4*)xt16;
    for (int u = tid; u < 900; u += 256) {
        int p = u / 9, s = u - p*9;
        uint4 v = make_uint4(0u, 0u, 0u, 0u);
        if (s < 8) {
            int g = s >> 1, half = s & 1;
            int r = p / 10, c = p - r*10;
            int y = ybase + r, xcc = xbase + c;
            if (y < 128 && xcc < 128)
                v = xc4[((size_t)(n*4 + g)*16384 + y*128 + xcc)*2 + half];
        }
        xt4[u] = v;
    }
    __syncthreads();

    const int w = tid >> 6, l = tid & 63;
    const int lg = l >> 4, ln = l & 15;
    float4v acc[4][4];
#pragma unroll
    for (int mi = 0; mi < 4; ++mi)
#pragma unroll
        for (int nt = 0; nt < 4; ++nt)
            acc[mi][nt] = (float4v){0.f, 0.f, 0.f, 0.f};

    const short8v* Bb = (const short8v*)pwB;
    for (int ks = 0; ks < 28; ++ks) {
        const int ky = ks >> 2, kxp = (ks & 3) << 1;
        short8v a[4], b[4];
#pragma unroll
        for (int mi = 0; mi < 4; ++mi) {
            int row = (4*w + mi) + ky;
            a[mi] = *(const short8v*)(tile + (row*24 + ln + kxp)*16 + lg*8);
        }
#pragma unroll
        for (int nt = 0; nt < 4; ++nt)
            b[nt] = Bb[ks*256 + nt*64 + ln*4 + lg];
#pragma unroll
        for (int mi = 0; mi < 4; ++mi)
#pragma unroll
            for (int nt = 0; nt < 4; ++nt)
                acc[mi][nt] = __builtin_amdgcn_mfma_f32_16x16x32_bf16(
                    a[mi], b[nt], acc[mi][nt], 0, 0, 0);
    }

    const int py = tid >> 4, pxx = tid & 15;
    const int ohy = oy + py, ohx = ox + pxx;
    float sy = ohy*SC, sx = ohx*SC;
    int y0 = min((int)sy, 126), x0 = min((int)sx, 126);
    float fy = sy - y0, fx = sx - x0;
    const int ly = y0 - ybase, lx = x0 - xbase;
    const int p = ohy*256 + ohx;
    const uint4* xt4c = (const uint4*)xt16;
    const size_t q00 = (size_t)(ly*10 + lx)*9;
    float kacc = akb[0];
    uint4* odst = (uint4*)oci + ((size_t)(n*65536 + p))*8;

    for (int nt = 0; nt < 4; ++nt) {
        __syncthreads();
#pragma unroll
        for (int mi = 0; mi < 4; ++mi)
#pragma unroll
            for (int r = 0; r < 4; ++r)
                P16[((4*w + mi)*16 + lg*4 + r)*17 + ln] = acc[mi][nt][r];
        __syncthreads();
        unsigned A00[8], A01[8], A10[8], A11[8];
        size_t qb = q00 + nt*2;
        load8(xt4c, qb,      A00);
        load8(xt4c, qb + 9,  A01);
        load8(xt4c, qb + 90, A10);
        load8(xt4c, qb + 99, A11);
        float u16[16];
#pragma unroll
        for (int h = 0; h < 8; ++h) {
            float l00, h00, l01, h01, l10, h10, l11, h11;
            unpack2(A00[h], l00, h00); unpack2(A01[h], l01, h01);
            unpack2(A10[h], l10, h10); unpack2(A11[h], l11, h11);
            u16[2*h]   = (l00*(1.f-fx) + l01*fx)*(1.f-fy) + (l10*(1.f-fx) + l11*fx)*fy;
            u16[2*h+1] = (h00*(1.f-fx) + h01*fx)*(1.f-fy) + (h10*(1.f-fx) + h11*fx)*fy;
        }
        unsigned qpk[8];
#pragma unroll
        for (int o = 0; o < 16; ++o) {
            int oc = nt*16 + o;
            u16[o] = P16[tid*17 + o] + bias[oc] + u16[o];
            kacc += akw[oc] * u16[o];
        }
#pragma unroll
        for (int h = 0; h < 8; ++h)
            qpk[h] = (unsigned)f2bf(u16[2*h]) | ((unsigned)f2bf(u16[2*h+1]) << 16);
        odst[nt*2]     = make_uint4(qpk[0], qpk[1], qpk[2], qpk[3]);
        odst[nt*2 + 1] = make_uint4(qpk[4], qpk[5], qpk[6], qpk[7]);
    }
    kbuf[n*65536 + p] = kacc;
}

// ---------------------------------------------------------------------------
// Softmax stats, stage 1 + stage 2.
// ---------------------------------------------------------------------------
__global__ __launch_bounds__(256) void softmax_part(
    const float* __restrict__ kb, float* __restrict__ pst)
{
    __shared__ float red[4];
    __shared__ float bcast;
    const int pc = blockIdx.x, n = blockIdx.y, tid = threadIdx.x;
    const float* kp = kb + n*65536 + pc*8192;
    float mx = -3.0e38f;
    for (int i = tid; i < 8192; i += 256) mx = fmaxf(mx, kp[i]);
#pragma unroll
    for (int off = 1; off < 64; off <<= 1) mx = fmaxf(mx, __shfl_xor(mx, off));
    int w = tid >> 6, l = tid & 63;
    if (l == 0) red[w] = mx;
    __syncthreads();
    if (tid == 0) bcast = fmaxf(fmaxf(red[0], red[1]), fmaxf(red[2], red[3]));
    __syncthreads();
    float BM = bcast;
    float s = 0.f;
    for (int i = tid; i < 8192; i += 256) s += __expf(kp[i] - BM);
#pragma unroll
    for (int off = 1; off < 64; off <<= 1) s += __shfl_xor(s, off);
    __syncthreads();
    if (l == 0) red[w] = s;
    __syncthreads();
    if (tid == 0) {
        pst[(n*8 + pc)*2]     = BM;
        pst[(n*8 + pc)*2 + 1] = red[0] + red[1] + red[2] + red[3];
    }
}

__global__ __launch_bounds__(64) void softmax_comb(
    const float* __restrict__ pst, float* __restrict__ st)
{
    int tid = threadIdx.x;
    if (tid < 8) {
        int n = tid;
        float MX = -3.0e38f;
        for (int c = 0; c < 8; ++c) MX = fmaxf(MX, pst[(n*8 + c)*2]);
        float S = 0.f;
        for (int c = 0; c < 8; ++c)
            S += pst[(n*8 + c)*2 + 1] * __expf(pst[(n*8 + c)*2] - MX);
        st[n] = MX; st[8 + n] = 1.f / S;
    }
}

// ---------------------------------------------------------------------------
// att_wsum on ci layout: Sp[n][pc][c] = sum_{p in chunk} exp(k-mx)*oci[p][c].
// ---------------------------------------------------------------------------
__global__ __launch_bounds__(256) void att_wsum(
    const unsigned short* __restrict__ oci, const float* __restrict__ kb,
    const float* __restrict__ st, float* __restrict__ Sp)
{
    const int pc = blockIdx.x, n = blockIdx.y, tid = threadIdx.x;
    const int qr = tid & 3, pidx0 = tid >> 2;   // 0..63
    const float mx = st[n];
    float acc[16];
#pragma unroll
    for (int c = 0; c < 16; ++c) acc[c] = 0.f;
    const float* kp = kb + n*65536 + pc*2048;
    const uint4* base = (const uint4*)oci + ((size_t)(n*65536 + pc*2048))*8 + qr*2;
    for (int p = pidx0; p < 2048; p += 64) {
        float e = __expf(kp[p] - mx);
        uint4 t0 = base[(size_t)p*8], t1 = base[(size_t)p*8 + 1];
        unsigned d[8] = {t0.x, t0.y, t0.z, t0.w, t1.x, t1.y, t1.z, t1.w};
#pragma unroll
        for (int h = 0; h < 8; ++h) {
            float lo, hi; unpack2(d[h], lo, hi);
            acc[2*h] += e*lo; acc[2*h + 1] += e*hi;
        }
    }
#pragma unroll
    for (int c = 0; c < 16; ++c) {
        acc[c] += __shfl_xor(acc[c], 4);
        acc[c] += __shfl_xor(acc[c], 8);
        acc[c] += __shfl_xor(acc[c], 16);
        acc[c] += __shfl_xor(acc[c], 32);
    }
    __shared__ float red[4][4][16];   // [wave][qr][ch]
    int w = tid >> 6, l = tid & 63;
    if (l < 4) {
#pragma unroll
        for (int c = 0; c < 16; ++c) red[w][l][c] = acc[c];
    }
    __syncthreads();
    if (tid < 64) {
        int q2 = tid >> 4, c = tid & 15;
        Sp[n*2048 + pc*64 + q2*16 + c] =
            red[0][q2][c] + red[1][q2][c] + red[2][q2][c] + red[3][q2][c];
    }
}

// ---------------------------------------------------------------------------
// context + per-(n,c) attention addend (parallel 32-chunk reduce).
// ---------------------------------------------------------------------------
__global__ __launch_bounds__(512) void ctx_addc(
    const float* __restrict__ Sp, const float* __restrict__ st,
    const float* __restrict__ avw, const float* __restrict__ avb,
    const float* __restrict__ arw, const float* __restrict__ arb,
    float* __restrict__ addc)
{
    __shared__ float Sf[512];
    __shared__ float ctx[8][8];
    const int tid = threadIdx.x;
    {
        int n = tid >> 6, c = tid & 63;
        float s = 0.f;
        for (int k = 0; k < 32; ++k) s += Sp[n*2048 + k*64 + c];
        Sf[n*64 + c] = s;
    }
    __syncthreads();
    if (tid < 64) {
        int n = tid >> 3, vc = tid & 7;
        float s = 0.f;
        for (int c = 0; c < 64; ++c) s += avw[vc*64 + c] * Sf[n*64 + c];
        ctx[n][vc] = s * st[8 + n] + avb[vc];
    }
    __syncthreads();
    int n = tid >> 6, c = tid & 63;
    float a = arb[c];
#pragma unroll
    for (int vc = 0; vc < 8; ++vc) a += arw[c*8 + vc] * ctx[n][vc];
    addc[n*64 + c] = a;
}

// ---------------------------------------------------------------------------
// Transformer via MFMA (R16 verified: bf16 oci in, f32 d_out once).
// ---------------------------------------------------------------------------
__global__ __launch_bounds__(256) void transformer_mfma(
    const unsigned short* __restrict__ oci, float* __restrict__ out,
    const float* __restrict__ addc,
    const float* __restrict__ lng, const float* __restrict__ lnb,
    const unsigned short* __restrict__ W1b, const float* __restrict__ fc1b,
    const unsigned short* __restrict__ W2b, const float* __restrict__ fc2b)
{
    __shared__ __align__(16) unsigned char lds[8448 + 9216 + 2048 + 256];
    unsigned* Xci = (unsigned*)lds;                           // [64 tok][33] uint
    unsigned short* Xcis = (unsigned short*)lds;              // ushort view [tok*66 + c]
    unsigned short* Xb = (unsigned short*)(lds + 8448);       // [64 tok][72] bf16
    unsigned short* Hb = Xb;                                  // aliases Xb
    float* ps  = (float*)(lds + 8448 + 9216);                 // [4][64]
    float* ps2 = ps + 256;                                    // [4][64]
    float* ach = ps2 + 256;                                   // [64]

    const int tid = threadIdx.x;
    const int n = blockIdx.x >> 10;
    const int p0 = (blockIdx.x & 1023) << 6;

    if (tid < 64) ach[tid] = addc[n*64 + tid];

    // Phase 1: coalesced uint4 loads -> uint stores into Xci
    const uint4* src = (const uint4*)oci + (size_t)(n*65536 + p0)*8;
#pragma unroll
    for (int k = 0; k < 2; ++k) {
        int v = k*256 + tid;
        int tok = v >> 3, part = v & 7;
        uint4 t = src[(size_t)tok*8 + part];
        unsigned* du = Xci + tok*33 + part*4;
        du[0] = t.x; du[1] = t.y; du[2] = t.z; du[3] = t.w;
    }
    __syncthreads();

    // Phase 2a: thread owns (token = tid&63, quarter q = tid>>6)
    const int token = tid & 63, q = tid >> 6;
    float t16[16];
    {
        float sum = 0.f, sq = 0.f;
#pragma unroll
        for (int e = 0; e < 16; ++e) {
            float v = bf2f(Xcis[token*66 + q*16 + e]) + ach[q*16 + e];
            t16[e] = v; sum += v; sq += v*v;
        }
        ps[q*64 + token] = sum; ps2[q*64 + token] = sq;
    }
    __syncthreads();
    // Phase 2b: finalize LN for own quarter, write Xb from registers.
    {
        float sum = ps[token] + ps[64 + token] + ps[128 + token] + ps[192 + token];
        float sq  = ps2[token] + ps2[64 + token] + ps2[128 + token] + ps2[192 + token];
        float mu = sum * (1.f/64.f);
        float var = fmaxf(sq * (1.f/64.f) - mu*mu, 0.f);
        float rs = rsqrtf(var + 1e-5f);
#pragma unroll
        for (int c8 = 0; c8 < 2; ++c8) {
            short8v pk;
#pragma unroll
            for (int e = 0; e < 8; ++e) {
                int c = q*16 + c8*8 + e;
                pk[e] = (short)f2bf((t16[c8*8 + e] - mu)*rs*lng[c] + lnb[c]);
            }
            *(short8v*)&Xb[token*72 + q*16 + c8*8] = pk;
        }
    }
    __syncthreads();

    const int w = tid >> 6, l = tid & 63, lg = l >> 4, ln = l & 15;

    // Phase 3: GEMM1 (wave w owns tokens w*16..w*16+15)
    float4v acc1[4];
#pragma unroll
    for (int nt = 0; nt < 4; ++nt) acc1[nt] = (float4v){0.f,0.f,0.f,0.f};
#pragma unroll
    for (int kk = 0; kk < 2; ++kk) {
        short8v a = *(const short8v*)&Xb[(w*16 + ln)*72 + kk*32 + lg*8];
        short8v b[4];
#pragma unroll
        for (int nt = 0; nt < 4; ++nt)
            b[nt] = *(const short8v*)&W1b[(nt*16 + ln)*64 + kk*32 + lg*8];
#pragma unroll
        for (int nt = 0; nt < 4; ++nt)
            acc1[nt] = __builtin_amdgcn_mfma_f32_16x16x32_bf16(a, b[nt], acc1[nt], 0, 0, 0);
    }
    __syncthreads();   // all waves done reading Xb before Hb (=Xb) writes
#pragma unroll
    for (int nt = 0; nt < 4; ++nt) {
        int j = nt*16 + ln;
        float bj = fc1b[j];
#pragma unroll
        for (int r = 0; r < 4; ++r) {
            int tok = w*16 + lg*4 + r;
            float m = acc1[nt][r] + bj;
            float g = 0.5f*m*(1.f + erff(m*0.70710678118654752f));
            Hb[tok*72 + j] = f2bf(g);
        }
    }
    __syncthreads();

    // Phase 4: GEMM2 + epilogue (residual unpacked from Xci + addc)
    float4v acc2[4];
#pragma unroll
    for (int nt = 0; nt < 4; ++nt) acc2[nt] = (float4v){0.f,0.f,0.f,0.f};
#pragma unroll
    for (int kk = 0; kk < 2; ++kk) {
        short8v a = *(const short8v*)&Hb[(w*16 + ln)*72 + kk*32 + lg*8];
        short8v b[4];
#pragma unroll
        for (int nt = 0; nt < 4; ++nt)
            b[nt] = *(const short8v*)&W2b[(nt*16 + ln)*64 + kk*32 + lg*8];
#pragma unroll
        for (int nt = 0; nt < 4; ++nt)
            acc2[nt] = __builtin_amdgcn_mfma_f32_16x16x32_bf16(a, b[nt], acc2[nt], 0, 0, 0);
    }
#pragma unroll
    for (int nt = 0; nt < 4; ++nt) {
        int c = nt*16 + ln;
        int tb = w*16 + lg*4;
        float add = fc2b[c] + ach[c];
        float* dst = out + (size_t)(n*64 + c)*HW256 + p0 + tb;
        float4v o;
#pragma unroll
        for (int r = 0; r < 4; ++r)
            o[r] = bf2f(Xcis[(tb + r)*66 + c]) + add + acc2[nt][r];
        *(float4v*)dst = o;
    }
}

// ---------------------------------------------------------------------------
extern "C" void kernel_launch(void* const* d_in, const int* in_sizes, int n_in,
                              void* d_out, int out_size, void* d_ws, size_t ws_size,
                              hipStream_t stream)
{
    (void)in_sizes; (void)n_in; (void)out_size; (void)ws_size;
    const float* x    = (const float*)d_in[0];
    const float* w7a  = (const float*)d_in[1];
    const float* b7a  = (const float*)d_in[2];
    const float* w1   = (const float*)d_in[3];
    const float* b1   = (const float*)d_in[4];
    const float* g1   = (const float*)d_in[5];
    const float* be1  = (const float*)d_in[6];
    const float* w3a  = (const float*)d_in[7];
    const float* b3a  = (const float*)d_in[8];
    const float* g3a  = (const float*)d_in[9];
    const float* be3a = (const float*)d_in[10];
    const float* w3b  = (const float*)d_in[11];
    const float* b3b  = (const float*)d_in[12];
    const float* g3b  = (const float*)d_in[13];
    const float* be3b = (const float*)d_in[14];
    const float* w3c  = (const float*)d_in[15];
    const float* b3c  = (const float*)d_in[16];
    const float* g3c  = (const float*)d_in[17];
    const float* be3c = (const float*)d_in[18];
    const float* w7b  = (const float*)d_in[19];
    const float* b7b  = (const float*)d_in[20];
    const float* akw  = (const float*)d_in[21];
    const float* akb  = (const float*)d_in[22];
    const float* avw  = (const float*)d_in[25];
    const float* avb  = (const float*)d_in[26];
    const float* arw  = (const float*)d_in[27];
    const float* arb  = (const float*)d_in[28];
    const float* lng  = (const float*)d_in[29];
    const float* lnb  = (const float*)d_in[30];
    const float* fc1w = (const float*)d_in[31];
    const float* fc1b = (const float*)d_in[32];
    const float* fc2w = (const float*)d_in[33];
    const float* fc2b = (const float*)d_in[34];

    float* ws = (float*)d_ws;
    unsigned short* y2ci = (unsigned short*)ws;                         // 2,097,152 sh
    unsigned short* yci  = (unsigned short*)(ws + 1048576);             // 8,388,608 sh
    unsigned short* z1ci = (unsigned short*)(ws + 1048576 + 4194304);   // (z1/z3)
    unsigned short* z2ci = (unsigned short*)(ws + 1048576 + 2*4194304);
    unsigned short* xci  = (unsigned short*)(ws + 1048576 + 3*4194304); // persists
    unsigned short* oci  = (unsigned short*)(ws + 1048576 + 4*4194304); // [8][65536][64] bf16
    float* o_k   = ws + 1048576 + 4*4194304 + 16777216;  // 524,288
    float* o_st  = o_k + 524288;                // 64
    float* o_pst = o_st + 64;                   // 128
    float* o_Sp  = o_pst + 128;                 // 16,384
    float* o_ad  = o_Sp + 16384;                // 512
    unsigned short* p7aB = (unsigned short*)(o_ad + 512);   // 57,344 sh
    float* p1   = o_ad + 512 + 28672;           // 256
    float* q3a  = p1 + 256;
    float* q3b  = q3a + 16;
    float* q3c  = q3b + 16;
    unsigned short* w3aB = (unsigned short*)(q3c + 16);     // 3,072 sh each
    unsigned short* w3bB = w3aB + 3072;
    unsigned short* w3cB = w3bB + 3072;
    unsigned short* pwB  = w3cB + 3072;                     // 57,344 sh
    unsigned short* pwT1 = pwB + 57344;                     // 4,096 sh
    unsigned short* pwT2 = pwT1 + 4096;                     // 4,096 sh

    unsigned short* z3ci = z1ci;
    float* out0 = (float*)d_out;

    prepack<<<224, 256, 0, stream>>>(w7a, w1, w3a,b3a,g3a,be3a, w3b,b3b,g3b,be3b,
                                     w3c,b3c,g3c,be3c, w7b, fc1w, fc2w,
                                     p7aB, p1, q3a, q3b, q3c, w3aB, w3bB, w3cB,
                                     pwB, pwT1, pwT2);
    x_to_ci<<<2048, 256, 0, stream>>>(x, xci);
    conv7a_mfma<<<dim3(8,8,8), 256, 0, stream>>>(xci, p7aB, b7a, p1, b1, g1, be1, y2ci);
    resize_ci<<<dim3(16,16,8), dim3(16,16), 0, stream>>>(y2ci, yci);
    conv3_mfma<0><<<dim3(16,16,8), 256, 0, stream>>>(yci,  w3aB, q3a, nullptr, z1ci);
    conv3_mfma<1><<<dim3(16,16,8), 256, 0, stream>>>(z1ci, w3bB, q3b, yci,     z2ci);
    conv3_mfma<1><<<dim3(16,16,8), 256, 0, stream>>>(z2ci, w3cB, q3c, yci,     z3ci);
    conv7b_mfma<<<dim3(16,16,8), 256, 0, stream>>>(z3ci, pwB, xci, b7b, akw, akb, oci, o_k);
    softmax_part<<<dim3(8,8), 256, 0, stream>>>(o_k, o_pst);
    softmax_comb<<<1, 64, 0, stream>>>(o_pst, o_st);
    att_wsum<<<dim3(32,8), 256, 0, stream>>>(oci, o_k, o_st, o_Sp);
    ctx_addc<<<1, 512, 0, stream>>>(o_Sp, o_st, avw, avb, arw, arb, o_ad);
    transformer_mfma<<<8192, 256, 0, stream>>>(oci, out0, o_ad, lng, lnb, pwT1, fc1b, pwT2, fc2b);
}